// Round 1
// baseline (905.631 us; speedup 1.0000x reference)
//
#include <hip/hip_runtime.h>
#include <math.h>

// ---------------------------------------------------------------------------
// cross_scale_attention: fp32 reference-accurate v1
//   q_fea = lrelu(conv3(pan, wq, bq))        [N,64,384,384]
//   k_fea = lrelu(conv3(pan2, wk, bk))       [N,64,96,96]
//   v_fea = lrelu(conv3(ms, wv, bv))         [N,8,96,96]
//   Kmat[n][l][c,kh,kw]  <- pad97+roll2 patch gather of k_fea  (+ norms)
//   Vt[n][(co,kh,kw)][l] <- same gather of v_fea (padded to 256 rows)
//   scale[n] = 10 / sqrt(max_l norms2)
//   per batch: Qmat[(c,kh,kw)][(y,x)] = q0[c][4y+kh][4x+kw] (385-pad)
//              scores = Kmat x Qmat        (576x1600 * 1600x9216)
//              softmax over l (x scale)
//              D = Vt x attn               (256x576 * 576x9216)
//              res[co][4y+kh][4x+kw] += D  (<=4-term gather), /6
//   out = lrelu(conv3(res, wr, br))          [N,8,385,385]
// ---------------------------------------------------------------------------

namespace csa {
constexpr int NB   = 2;
constexpr int MID  = 64;
constexpr int BAND = 8;
constexpr int HK   = 96;
constexpr int HQ   = 384;
constexpr int LN   = 24;
constexpr int L    = 576;   // LN*LN
constexpr int PS   = 96 * 96;       // 9216 score positions
constexpr int KDIM = MID * 25;      // 1600
constexpr int VDIM = BAND * 25;     // 200
constexpr int MV   = 256;           // VDIM padded for GEMM
constexpr int HO   = 385;

constexpr size_t SZ_QFEA  = (size_t)NB * MID * HQ * HQ;   // 18.9M
constexpr size_t SZ_KFEA  = (size_t)NB * MID * HK * HK;
constexpr size_t SZ_VFEA  = (size_t)NB * BAND * HK * HK;
constexpr size_t SZ_KMAT  = (size_t)NB * L * KDIM;
constexpr size_t SZ_VT    = (size_t)NB * MV * L;
constexpr size_t SZ_N2    = (size_t)NB * L;
constexpr size_t SZ_SC    = 4;
constexpr size_t SZ_QMAT  = (size_t)KDIM * PS;            // 14.7M (per-batch reuse)
constexpr size_t SZ_SCORE = (size_t)L * PS;               // 5.3M  (per-batch reuse)
constexpr size_t SZ_D     = (size_t)MV * PS;              // 2.36M (per-batch reuse)

constexpr size_t OFF_QFEA  = 0;
constexpr size_t OFF_KFEA  = OFF_QFEA + SZ_QFEA;
constexpr size_t OFF_VFEA  = OFF_KFEA + SZ_KFEA;
constexpr size_t OFF_KMAT  = OFF_VFEA + SZ_VFEA;
constexpr size_t OFF_VT    = OFF_KMAT + SZ_KMAT;
constexpr size_t OFF_N2    = OFF_VT + SZ_VT;
constexpr size_t OFF_SC    = OFF_N2 + SZ_N2;
constexpr size_t OFF_QMAT  = OFF_SC + SZ_SC;
constexpr size_t OFF_SCORE = OFF_QMAT + SZ_QMAT;
constexpr size_t OFF_D     = OFF_SCORE + SZ_SCORE;
constexpr size_t OFF_RES   = OFF_D + SZ_D;
// total ~47.1M floats = 188.5 MB of d_ws
}  // namespace csa

using namespace csa;

// ------------------------- conv3: 1 in-ch -> 64 out-ch ----------------------
__global__ __launch_bounds__(256) void csa_conv3_1x64(
    const float* __restrict__ in, const float* __restrict__ w,
    const float* __restrict__ b, float* __restrict__ out, int H, int W) {
  int id = blockIdx.x * 256 + threadIdx.x;
  int total = NB * H * W;
  if (id >= total) return;
  int x = id % W;
  int t = id / W;
  int y = t % H;
  int n = t / H;
  const float* ip = in + (size_t)n * H * W;
  float p[9];
#pragma unroll
  for (int dy = 0; dy < 3; ++dy)
#pragma unroll
    for (int dx = 0; dx < 3; ++dx) {
      int yy = y + dy - 1, xx = x + dx - 1;
      p[dy * 3 + dx] = (yy >= 0 && yy < H && xx >= 0 && xx < W)
                           ? ip[(size_t)yy * W + xx] : 0.f;
    }
  float* op = out + ((size_t)n * MID * H + y) * W + x;
  for (int co = 0; co < MID; ++co) {
    float acc = b[co];
#pragma unroll
    for (int k = 0; k < 9; ++k) acc = fmaf(p[k], w[co * 9 + k], acc);
    acc = acc > 0.f ? acc : 0.01f * acc;
    op[(size_t)co * H * W] = acc;
  }
}

// ------------------------- conv3: 8 in-ch -> 8 out-ch -----------------------
__global__ __launch_bounds__(256) void csa_conv3_8x8(
    const float* __restrict__ in, const float* __restrict__ w,
    const float* __restrict__ b, float* __restrict__ out, int H, int W) {
  int id = blockIdx.x * 256 + threadIdx.x;
  int total = NB * H * W;
  if (id >= total) return;
  int x = id % W;
  int t = id / W;
  int y = t % H;
  int n = t / H;
  const float* ip = in + (size_t)n * BAND * H * W;
  float p[BAND][9];
#pragma unroll
  for (int ci = 0; ci < BAND; ++ci)
#pragma unroll
    for (int dy = 0; dy < 3; ++dy)
#pragma unroll
      for (int dx = 0; dx < 3; ++dx) {
        int yy = y + dy - 1, xx = x + dx - 1;
        p[ci][dy * 3 + dx] = (yy >= 0 && yy < H && xx >= 0 && xx < W)
                                 ? ip[((size_t)ci * H + yy) * W + xx] : 0.f;
      }
  float* op = out + ((size_t)n * BAND * H + y) * W + x;
  for (int co = 0; co < BAND; ++co) {
    float acc = b[co];
#pragma unroll
    for (int ci = 0; ci < BAND; ++ci)
#pragma unroll
      for (int k = 0; k < 9; ++k)
        acc = fmaf(p[ci][k], w[(co * BAND + ci) * 9 + k], acc);
    acc = acc > 0.f ? acc : 0.01f * acc;
    op[(size_t)co * H * W] = acc;
  }
}

// ------------- patch gather: Kmat[l][k], Vt[m][l], per-patch norms ----------
// patch(i,j) elem (c,kh,kw) = fea[c][(4i+kh-2) mod 97][(4j+kw-2) mod 97],
// index 96 (the SAME-pad row/col) -> 0.
__global__ __launch_bounds__(256) void csa_build_patches(
    const float* __restrict__ k_fea, const float* __restrict__ v_fea,
    float* __restrict__ Kmat, float* __restrict__ Vt, float* __restrict__ n2) {
  int blk = blockIdx.x;           // NB*L blocks
  int n = blk / L;
  int l = blk % L;
  int i = l / LN, j = l % LN;
  int tid = threadIdx.x;
  float ss = 0.f;
  for (int k = tid; k < KDIM; k += 256) {
    int kw = k % 5;
    int t = k / 5;
    int kh = t % 5;
    int c = t / 5;
    int r = (4 * i + kh + 95) % 97;
    int cc = (4 * j + kw + 95) % 97;
    float v = (r < 96 && cc < 96)
                  ? k_fea[(((size_t)n * MID + c) * HK + r) * HK + cc] : 0.f;
    Kmat[((size_t)n * L + l) * KDIM + k] = v;
    ss += v * v;
  }
  for (int m = tid; m < MV; m += 256) {
    float v = 0.f;
    if (m < VDIM) {
      int kw = m % 5;
      int t = m / 5;
      int kh = t % 5;
      int c = t / 5;
      int r = (4 * i + kh + 95) % 97;
      int cc = (4 * j + kw + 95) % 97;
      v = (r < 96 && cc < 96)
              ? v_fea[(((size_t)n * BAND + c) * HK + r) * HK + cc] : 0.f;
    }
    Vt[((size_t)n * MV + m) * L + l] = v;
  }
  __shared__ float red[256];
  red[tid] = ss;
  __syncthreads();
  for (int s = 128; s > 0; s >>= 1) {
    if (tid < s) red[tid] += red[tid + s];
    __syncthreads();
  }
  if (tid == 0) n2[n * L + l] = red[0];
}

// ---------------- scale[n] = 10 / sqrt(max_l norms2[n][l]) ------------------
__global__ __launch_bounds__(256) void csa_max_scale(
    const float* __restrict__ n2, float* __restrict__ scale) {
  int n = blockIdx.x;
  int tid = threadIdx.x;
  float m = 0.f;
  for (int l = tid; l < L; l += 256) m = fmaxf(m, n2[n * L + l]);
  __shared__ float red[256];
  red[tid] = m;
  __syncthreads();
  for (int s = 128; s > 0; s >>= 1) {
    if (tid < s) red[tid] = fmaxf(red[tid], red[tid + s]);
    __syncthreads();
  }
  if (tid == 0) scale[n] = 10.f / sqrtf(red[0]);
}

// -------- Qmat[(c,kh,kw)][(y,x)] = q0[c][4y+kh][4x+kw] (row/col 384 -> 0) ---
__global__ __launch_bounds__(256) void csa_build_qmat(
    const float* __restrict__ qf, float* __restrict__ Qmat) {
  int id = blockIdx.x * 256 + threadIdx.x;
  if (id >= KDIM * PS) return;
  int p = id % PS;
  int k = id / PS;
  int y = p / 96;
  int x = p % 96;
  int kw = k % 5;
  int t = k / 5;
  int kh = t % 5;
  int c = t / 5;
  int row = 4 * y + kh;
  int col = 4 * x + kw;
  float v = (row < HQ && col < HQ) ? qf[((size_t)c * HQ + row) * HQ + col] : 0.f;
  Qmat[id] = v;
}

// ----------------- fp32 GEMM: C[M][Nn] = A[M][K] * B[K][Nn] -----------------
// BM=64 BN=128 BK=16, 256 threads, 4x8 register tile. M%64==0, Nn%128==0,
// K%16==0 required.
__global__ __launch_bounds__(256) void csa_gemm_f32(
    const float* __restrict__ A, const float* __restrict__ B,
    float* __restrict__ C, int M, int K, int Nn) {
  constexpr int BM = 64, BN = 128, BK = 16;
  __shared__ __align__(16) float As[BK][BM];
  __shared__ __align__(16) float Bs[BK][BN];
  const int tid = threadIdx.x;
  const int bm = blockIdx.y * BM;
  const int bn = blockIdx.x * BN;
  const int tm4 = (tid >> 4) * 4;   // 0..60
  const int tn4 = (tid & 15) * 4;   // 0..60 ; cols tn4..tn4+3 and tn4+64..+67
  float acc[4][8];
#pragma unroll
  for (int i = 0; i < 4; ++i)
#pragma unroll
    for (int j = 0; j < 8; ++j) acc[i][j] = 0.f;

  const int a_row = tid >> 2;        // 0..63
  const int a_col = (tid & 3) * 4;   // 0,4,8,12
  const int b_row = tid >> 5;        // 0..7 (and +8)
  const int b_col = (tid & 31) * 4;  // 0..124

  const float* Ag = A + (size_t)(bm + a_row) * K + a_col;
  const float* Bg0 = B + (size_t)b_row * Nn + bn + b_col;
  const float* Bg1 = Bg0 + (size_t)8 * Nn;

  for (int k0 = 0; k0 < K; k0 += BK) {
    float4 av = *(const float4*)(Ag + k0);
    float4 bv0 = *(const float4*)(Bg0 + (size_t)k0 * Nn);
    float4 bv1 = *(const float4*)(Bg1 + (size_t)k0 * Nn);
    As[a_col + 0][a_row] = av.x;
    As[a_col + 1][a_row] = av.y;
    As[a_col + 2][a_row] = av.z;
    As[a_col + 3][a_row] = av.w;
    *(float4*)&Bs[b_row][b_col] = bv0;
    *(float4*)&Bs[b_row + 8][b_col] = bv1;
    __syncthreads();
#pragma unroll
    for (int kk = 0; kk < BK; ++kk) {
      float4 a = *(const float4*)&As[kk][tm4];
      float4 b0 = *(const float4*)&Bs[kk][tn4];
      float4 b1 = *(const float4*)&Bs[kk][tn4 + 64];
      float ar[4] = {a.x, a.y, a.z, a.w};
      float br[8] = {b0.x, b0.y, b0.z, b0.w, b1.x, b1.y, b1.z, b1.w};
#pragma unroll
      for (int i = 0; i < 4; ++i)
#pragma unroll
        for (int j = 0; j < 8; ++j) acc[i][j] = fmaf(ar[i], br[j], acc[i][j]);
    }
    __syncthreads();
  }
#pragma unroll
  for (int i = 0; i < 4; ++i) {
    float4 o0 = make_float4(acc[i][0], acc[i][1], acc[i][2], acc[i][3]);
    float4 o1 = make_float4(acc[i][4], acc[i][5], acc[i][6], acc[i][7]);
    *(float4*)(C + (size_t)(bm + tm4 + i) * Nn + bn + tn4) = o0;
    *(float4*)(C + (size_t)(bm + tm4 + i) * Nn + bn + tn4 + 64) = o1;
  }
}

// ------------- softmax over l (576) per column p, in place, x scale ---------
// 256 threads = 64 columns x 4 l-groups of 144.
__global__ __launch_bounds__(256) void csa_softmax(
    float* __restrict__ scores, const float* __restrict__ scale_p) {
  const float sc = *scale_p;
  const int c = threadIdx.x & 63;
  const int g = threadIdx.x >> 6;  // 0..3
  const int p = blockIdx.x * 64 + c;
  const int l0 = g * (L / 4);
  float m = -1e30f, s = 0.f;
  for (int l = l0; l < l0 + L / 4; ++l) {
    float v = scores[(size_t)l * PS + p] * sc;
    float nm = fmaxf(m, v);
    s = s * __expf(m - nm) + __expf(v - nm);
    m = nm;
  }
  __shared__ float Ms[4][64], Ss[4][64];
  Ms[g][c] = m;
  Ss[g][c] = s;
  __syncthreads();
  float M = fmaxf(fmaxf(Ms[0][c], Ms[1][c]), fmaxf(Ms[2][c], Ms[3][c]));
  float S = Ss[0][c] * __expf(Ms[0][c] - M) + Ss[1][c] * __expf(Ms[1][c] - M) +
            Ss[2][c] * __expf(Ms[2][c] - M) + Ss[3][c] * __expf(Ms[3][c] - M);
  float inv = 1.f / S;
  for (int l = l0; l < l0 + L / 4; ++l) {
    float v = scores[(size_t)l * PS + p] * sc;
    scores[(size_t)l * PS + p] = __expf(v - M) * inv;
  }
}

// ------ conv_transpose overlap gather: res[co][oy][ox] = sum D / 6 ----------
__global__ __launch_bounds__(256) void csa_gather(
    const float* __restrict__ D, float* __restrict__ res) {
  int id = blockIdx.x * 256 + threadIdx.x;
  if (id >= BAND * HO * HO) return;
  int ox = id % HO;
  int t = id / HO;
  int oy = t % HO;
  int co = t / HO;
  float s = 0.f;
  int kh0 = oy & 3;
  int kw0 = ox & 3;
  for (int kh = kh0; kh < 5; kh += 4) {
    int y = (oy - kh) >> 2;
    if (y < 0 || y >= 96) continue;
    for (int kw = kw0; kw < 5; kw += 4) {
      int x = (ox - kw) >> 2;
      if (x < 0 || x >= 96) continue;
      s += D[(size_t)(co * 25 + kh * 5 + kw) * PS + y * 96 + x];
    }
  }
  res[id] = s * (1.f / 6.f);
}

// ---------------------------------------------------------------------------
extern "C" void kernel_launch(void* const* d_in, const int* in_sizes, int n_in,
                              void* d_out, int out_size, void* d_ws,
                              size_t ws_size, hipStream_t stream) {
  const float* ms   = (const float*)d_in[0];
  const float* pan  = (const float*)d_in[1];
  const float* pan2 = (const float*)d_in[2];
  const float* wq = (const float*)d_in[3];
  const float* bq = (const float*)d_in[4];
  const float* wk = (const float*)d_in[5];
  const float* bk = (const float*)d_in[6];
  const float* wv = (const float*)d_in[7];
  const float* bv = (const float*)d_in[8];
  const float* wr = (const float*)d_in[9];
  const float* br = (const float*)d_in[10];
  float* out = (float*)d_out;

  float* ws = (float*)d_ws;
  float* q_fea = ws + OFF_QFEA;
  float* k_fea = ws + OFF_KFEA;
  float* v_fea = ws + OFF_VFEA;
  float* Kmat  = ws + OFF_KMAT;
  float* Vt    = ws + OFF_VT;
  float* n2    = ws + OFF_N2;
  float* scale = ws + OFF_SC;
  float* Qmat  = ws + OFF_QMAT;
  float* score = ws + OFF_SCORE;
  float* Dm    = ws + OFF_D;
  float* res   = ws + OFF_RES;

  dim3 b256(256);
  csa_conv3_1x64<<<dim3((NB * HQ * HQ + 255) / 256), b256, 0, stream>>>(
      pan, wq, bq, q_fea, HQ, HQ);
  csa_conv3_1x64<<<dim3((NB * HK * HK + 255) / 256), b256, 0, stream>>>(
      pan2, wk, bk, k_fea, HK, HK);
  csa_conv3_8x8<<<dim3((NB * HK * HK + 255) / 256), b256, 0, stream>>>(
      ms, wv, bv, v_fea, HK, HK);
  csa_build_patches<<<dim3(NB * L), b256, 0, stream>>>(k_fea, v_fea, Kmat, Vt,
                                                       n2);
  csa_max_scale<<<dim3(NB), b256, 0, stream>>>(n2, scale);

  for (int n = 0; n < NB; ++n) {
    csa_build_qmat<<<dim3(KDIM * PS / 256), b256, 0, stream>>>(
        q_fea + (size_t)n * MID * HQ * HQ, Qmat);
    csa_gemm_f32<<<dim3(PS / 128, L / 64), b256, 0, stream>>>(
        Kmat + (size_t)n * L * KDIM, Qmat, score, L, KDIM, PS);
    csa_softmax<<<dim3(PS / 64), b256, 0, stream>>>(score, scale + n);
    csa_gemm_f32<<<dim3(PS / 128, MV / 64), b256, 0, stream>>>(
        Vt + (size_t)n * MV * L, score, Dm, MV, L, PS);
    csa_gather<<<dim3((BAND * HO * HO + 255) / 256), b256, 0, stream>>>(
        Dm, res + (size_t)n * BAND * HO * HO);
  }
  csa_conv3_8x8<<<dim3((NB * HO * HO + 255) / 256), b256, 0, stream>>>(
      res, wr, br, out, HO, HO);
}

// Round 2
// 553.218 us; speedup vs baseline: 1.6370x; 1.6370x over previous
//
#include <hip/hip_runtime.h>
#include <math.h>

// ---------------------------------------------------------------------------
// cross_scale_attention v2: f16 MFMA GEMMs (fp32 accumulate)
//   k_fea = lrelu(conv3(pan2, wk, bk))  fp32 [N,64,96,96]
//   v_fea = lrelu(conv3(ms, wv, bv))    fp32 [N,8,96,96]
//   QmatT[n][p][k]  (f16) <- fused conv3(pan, wq, bq) + patch expand
//   Kmat[n][l][k]   (f16, 640 rows, pad zeros) + per-patch norms
//   Vt[n][m][l]     (f16, 256x576, pad zeros)
//   scoresT[n][p][l640] = QmatT x Kmat^T      (MFMA GEMM1)
//   attnT[n][p][l]  (f16) = softmax rows * 10/maxnorm
//   D[n][m][p]      = Vt x attnT^T            (MFMA GEMM2)
//   res gather (/6), final conv3 8x8 -> out fp32
// ---------------------------------------------------------------------------

typedef _Float16 f16;
typedef _Float16 f16x8 __attribute__((ext_vector_type(8)));
typedef float f32x4 __attribute__((ext_vector_type(4)));

namespace csa {
constexpr int NB   = 2;
constexpr int MID  = 64;
constexpr int BAND = 8;
constexpr int HK   = 96;
constexpr int HQ   = 384;
constexpr int LN   = 24;
constexpr int L    = 576;
constexpr int LP   = 640;           // L padded to 128 multiple
constexpr int PS   = 96 * 96;       // 9216
constexpr int KDIM = MID * 25;      // 1600
constexpr int VDIM = BAND * 25;     // 200
constexpr int MV   = 256;
constexpr int HO   = 385;

// byte offsets into d_ws (all 256-aligned)
constexpr size_t align256(size_t x) { return (x + 255) & ~(size_t)255; }
constexpr size_t OFF_KFEA = 0;                                            // f32 NB*64*96*96
constexpr size_t OFF_VFEA = align256(OFF_KFEA + (size_t)NB*MID*HK*HK*4);  // f32 NB*8*96*96
constexpr size_t OFF_N2   = align256(OFF_VFEA + (size_t)NB*BAND*HK*HK*4); // f32 NB*576
constexpr size_t OFF_SC   = align256(OFF_N2   + (size_t)NB*L*4);          // f32 NB
constexpr size_t OFF_KM   = align256(OFF_SC   + 256);                     // f16 NB*640*1600
constexpr size_t OFF_VT   = align256(OFF_KM   + (size_t)NB*LP*KDIM*2);    // f16 NB*256*576
constexpr size_t OFF_QT   = align256(OFF_VT   + (size_t)NB*MV*L*2);       // f16 NB*9216*1600
constexpr size_t OFF_ST   = align256(OFF_QT   + (size_t)NB*PS*KDIM*2);    // f32 NB*9216*640
constexpr size_t OFF_AT   = align256(OFF_ST   + (size_t)NB*PS*LP*4);      // f16 NB*9216*576
constexpr size_t OFF_D    = align256(OFF_AT   + (size_t)NB*PS*L*2);       // f32 NB*256*9216
constexpr size_t OFF_RES  = align256(OFF_D    + (size_t)NB*MV*PS*4);      // f32 NB*8*385*385
}  // namespace csa
using namespace csa;

// ------------------------- conv3: 1 in-ch -> 64 out-ch ----------------------
__global__ __launch_bounds__(256) void csa_conv3_1x64(
    const float* __restrict__ in, const float* __restrict__ w,
    const float* __restrict__ b, float* __restrict__ out, int H, int W) {
  int id = blockIdx.x * 256 + threadIdx.x;
  int total = NB * H * W;
  if (id >= total) return;
  int x = id % W;
  int t = id / W;
  int y = t % H;
  int n = t / H;
  const float* ip = in + (size_t)n * H * W;
  float p[9];
#pragma unroll
  for (int dy = 0; dy < 3; ++dy)
#pragma unroll
    for (int dx = 0; dx < 3; ++dx) {
      int yy = y + dy - 1, xx = x + dx - 1;
      p[dy * 3 + dx] = (yy >= 0 && yy < H && xx >= 0 && xx < W)
                           ? ip[(size_t)yy * W + xx] : 0.f;
    }
  float* op = out + ((size_t)n * MID * H + y) * W + x;
  for (int co = 0; co < MID; ++co) {
    float acc = b[co];
#pragma unroll
    for (int k = 0; k < 9; ++k) acc = fmaf(p[k], w[co * 9 + k], acc);
    acc = acc > 0.f ? acc : 0.01f * acc;
    op[(size_t)co * H * W] = acc;
  }
}

// ------------------------- conv3: 8 in-ch -> 8 out-ch -----------------------
__global__ __launch_bounds__(256) void csa_conv3_8x8(
    const float* __restrict__ in, const float* __restrict__ w,
    const float* __restrict__ b, float* __restrict__ out, int H, int W) {
  int id = blockIdx.x * 256 + threadIdx.x;
  int total = NB * H * W;
  if (id >= total) return;
  int x = id % W;
  int t = id / W;
  int y = t % H;
  int n = t / H;
  const float* ip = in + (size_t)n * BAND * H * W;
  float p[BAND][9];
#pragma unroll
  for (int ci = 0; ci < BAND; ++ci)
#pragma unroll
    for (int dy = 0; dy < 3; ++dy)
#pragma unroll
      for (int dx = 0; dx < 3; ++dx) {
        int yy = y + dy - 1, xx = x + dx - 1;
        p[ci][dy * 3 + dx] = (yy >= 0 && yy < H && xx >= 0 && xx < W)
                                 ? ip[((size_t)ci * H + yy) * W + xx] : 0.f;
      }
  float* op = out + ((size_t)n * BAND * H + y) * W + x;
  for (int co = 0; co < BAND; ++co) {
    float acc = b[co];
#pragma unroll
    for (int ci = 0; ci < BAND; ++ci)
#pragma unroll
      for (int k = 0; k < 9; ++k)
        acc = fmaf(p[ci][k], w[(co * BAND + ci) * 9 + k], acc);
    acc = acc > 0.f ? acc : 0.01f * acc;
    op[(size_t)co * H * W] = acc;
  }
}

// ------- fused conv3(pan,wq,bq) + patch expand -> QmatT[n][p][k] f16 --------
__global__ __launch_bounds__(256) void csa_qmat(
    const float* __restrict__ pan, const float* __restrict__ wq,
    const float* __restrict__ bq, f16* __restrict__ Qt) {
  size_t id = (size_t)blockIdx.x * 256 + threadIdx.x;
  int k = (int)(id % KDIM);
  size_t t = id / KDIM;
  int p = (int)(t % PS);
  int n = (int)(t / PS);
  int kw = k % 5;
  int t2 = k / 5;
  int kh = t2 % 5;
  int c = t2 / 5;
  int y = p / 96, x = p % 96;
  int row = 4 * y + kh, col = 4 * x + kw;
  float v = 0.f;
  if (row < HQ && col < HQ) {
    const float* ip = pan + (size_t)n * HQ * HQ;
    float acc = bq[c];
#pragma unroll
    for (int dy = 0; dy < 3; ++dy)
#pragma unroll
      for (int dx = 0; dx < 3; ++dx) {
        int yy = row + dy - 1, xx = col + dx - 1;
        float pv = (yy >= 0 && yy < HQ && xx >= 0 && xx < HQ)
                       ? ip[(size_t)yy * HQ + xx] : 0.f;
        acc = fmaf(pv, wq[c * 9 + dy * 3 + dx], acc);
      }
    v = acc > 0.f ? acc : 0.01f * acc;
  }
  Qt[id] = (f16)v;
}

// ---- patch gather: Kmat[l][k] f16 (pad rows zero), Vt[m][l] f16, norms² ----
__global__ __launch_bounds__(256) void csa_build_patches(
    const float* __restrict__ k_fea, const float* __restrict__ v_fea,
    f16* __restrict__ Kmat, f16* __restrict__ Vt, float* __restrict__ n2) {
  int blk = blockIdx.x;  // NB*LP blocks
  int n = blk / LP;
  int l = blk % LP;
  int tid = threadIdx.x;
  if (l >= L) {  // zero-pad rows
    for (int k = tid; k < KDIM; k += 256)
      Kmat[((size_t)n * LP + l) * KDIM + k] = (f16)0.f;
    return;
  }
  int i = l / LN, j = l % LN;
  float ss = 0.f;
  for (int k = tid; k < KDIM; k += 256) {
    int kw = k % 5;
    int t = k / 5;
    int kh = t % 5;
    int c = t / 5;
    int r = (4 * i + kh + 95) % 97;
    int cc = (4 * j + kw + 95) % 97;
    float v = (r < 96 && cc < 96)
                  ? k_fea[(((size_t)n * MID + c) * HK + r) * HK + cc] : 0.f;
    Kmat[((size_t)n * LP + l) * KDIM + k] = (f16)v;
    ss += v * v;
  }
  for (int m = tid; m < MV; m += 256) {
    float v = 0.f;
    if (m < VDIM) {
      int kw = m % 5;
      int t = m / 5;
      int kh = t % 5;
      int c = t / 5;
      int r = (4 * i + kh + 95) % 97;
      int cc = (4 * j + kw + 95) % 97;
      v = (r < 96 && cc < 96)
              ? v_fea[(((size_t)n * BAND + c) * HK + r) * HK + cc] : 0.f;
    }
    Vt[((size_t)n * MV + m) * L + l] = (f16)v;
  }
  __shared__ float red[256];
  red[tid] = ss;
  __syncthreads();
  for (int s = 128; s > 0; s >>= 1) {
    if (tid < s) red[tid] += red[tid + s];
    __syncthreads();
  }
  if (tid == 0) n2[n * L + l] = red[0];
}

// ---------------- scale[n] = 10 / sqrt(max_l norms2[n][l]) ------------------
__global__ __launch_bounds__(256) void csa_max_scale(
    const float* __restrict__ n2, float* __restrict__ scale) {
  int n = blockIdx.x;
  int tid = threadIdx.x;
  float m = 0.f;
  for (int l = tid; l < L; l += 256) m = fmaxf(m, n2[n * L + l]);
  __shared__ float red[256];
  red[tid] = m;
  __syncthreads();
  for (int s = 128; s > 0; s >>= 1) {
    if (tid < s) red[tid] = fmaxf(red[tid], red[tid + s]);
    __syncthreads();
  }
  if (tid == 0) scale[n] = 10.f / sqrtf(red[0]);
}

// --------------------- f16 MFMA GEMM (m97-style) ----------------------------
// C[M][N] fp32 = A[M][K] f16 row-major  x  B (as Bt[N][K] f16 row-major).
// BM=BN=128, BK=32, 256 threads = 4 waves (2x2 of 64x64), 16x16x32 MFMA.
// LDS in fragment order: chunk(m>>4)*512 + (k>>3 quad)*128 + (m&15)*8 f16.
// Staged via global_load_lds width 16 (lane scatter = base + lane*16B).
// Requires M%128==0, N%128==0, K%32==0, rows 16B-aligned (K%8==0).
__device__ __forceinline__ void gl_lds16(const f16* g, f16* s) {
  __builtin_amdgcn_global_load_lds(
      (const __attribute__((address_space(1))) void*)g,
      (__attribute__((address_space(3))) void*)s, 16, 0, 0);
}

__global__ __launch_bounds__(256) void csa_gemm_f16(
    const f16* __restrict__ A, const f16* __restrict__ Bt,
    float* __restrict__ C, int M, int N, int K,
    size_t strideA, size_t strideB, size_t strideC) {
  __shared__ __attribute__((aligned(16))) f16 As[4096];
  __shared__ __attribute__((aligned(16))) f16 Bs[4096];
  const int tid = threadIdx.x;
  const int w = tid >> 6;
  const int l = tid & 63;
  const int q = l >> 4;
  const int r = l & 15;
  const int nb = blockIdx.z;
  A += (size_t)nb * strideA;
  Bt += (size_t)nb * strideB;
  C += (size_t)nb * strideC;
  const int bm = blockIdx.y * 128;
  const int bn = blockIdx.x * 128;
  const int wm = (w >> 1) * 64;
  const int wn = (w & 1) * 64;

  f32x4 acc[4][4];
#pragma unroll
  for (int i = 0; i < 4; ++i)
#pragma unroll
    for (int j = 0; j < 4; ++j) {
      f32x4 z = {0.f, 0.f, 0.f, 0.f};
      acc[i][j] = z;
    }

  // staging: issue i, wave w covers rows bm + i*64 + w*16 + r, cols q*8..q*8+7
  const f16* ga0 = A + (size_t)(bm + w * 16 + r) * K + q * 8;
  const f16* ga1 = ga0 + (size_t)64 * K;
  const f16* gb0 = Bt + (size_t)(bn + w * 16 + r) * K + q * 8;
  const f16* gb1 = gb0 + (size_t)64 * K;
  f16* lA0 = As + w * 512;         // + lane*8 f16 implicit
  f16* lA1 = As + 2048 + w * 512;
  f16* lB0 = Bs + w * 512;
  f16* lB1 = Bs + 2048 + w * 512;

  const int am = (w >> 1) * 4;  // A chunk base (m>>4) for this wave
  const int bnn = (w & 1) * 4;

  for (int k0 = 0; k0 < K; k0 += 32) {
    gl_lds16(ga0 + k0, lA0);
    gl_lds16(ga1 + k0, lA1);
    gl_lds16(gb0 + k0, lB0);
    gl_lds16(gb1 + k0, lB1);
    __syncthreads();
    f16x8 af[4], bf[4];
#pragma unroll
    for (int t = 0; t < 4; ++t) {
      af[t] = *(const f16x8*)&As[(am + t) * 512 + q * 128 + r * 8];
      bf[t] = *(const f16x8*)&Bs[(bnn + t) * 512 + q * 128 + r * 8];
    }
#pragma unroll
    for (int i = 0; i < 4; ++i)
#pragma unroll
      for (int j = 0; j < 4; ++j)
        acc[i][j] =
            __builtin_amdgcn_mfma_f32_16x16x32_f16(af[i], bf[j], acc[i][j], 0, 0, 0);
    __syncthreads();
  }

  // epilogue: C[m = bm+wm+i*16+q*4+rr][n = bn+wn+j*16+r]
  const int cn = bn + wn + r;
#pragma unroll
  for (int i = 0; i < 4; ++i) {
    int rm = bm + wm + i * 16 + q * 4;
#pragma unroll
    for (int j = 0; j < 4; ++j) {
#pragma unroll
      for (int rr = 0; rr < 4; ++rr)
        C[(size_t)(rm + rr) * N + cn + j * 16] = acc[i][j][rr];
    }
  }
}

// ------- row softmax: attnT[p][l] f16 = softmax_l(scoresT[p][l]*scale) ------
// one wave per row p; 576 = 9*64
__global__ __launch_bounds__(256) void csa_softmax(
    const float* __restrict__ scoresT, const float* __restrict__ scale,
    f16* __restrict__ attnT) {
  const int wv = threadIdx.x >> 6;
  const int lane = threadIdx.x & 63;
  const int p = blockIdx.x * 4 + wv;
  const int n = blockIdx.y;
  const float sc = scale[n];
  const float* row = scoresT + ((size_t)n * PS + p) * LP;
  float v[9];
  float m = -1e30f;
#pragma unroll
  for (int j = 0; j < 9; ++j) {
    v[j] = row[lane + j * 64] * sc;
    m = fmaxf(m, v[j]);
  }
#pragma unroll
  for (int off = 32; off > 0; off >>= 1) m = fmaxf(m, __shfl_xor(m, off));
  float e[9], s = 0.f;
#pragma unroll
  for (int j = 0; j < 9; ++j) {
    e[j] = __expf(v[j] - m);
    s += e[j];
  }
#pragma unroll
  for (int off = 32; off > 0; off >>= 1) s += __shfl_xor(s, off);
  const float inv = 1.f / s;
  f16* orow = attnT + ((size_t)n * PS + p) * L;
#pragma unroll
  for (int j = 0; j < 9; ++j) orow[lane + j * 64] = (f16)(e[j] * inv);
}

// ------ conv_transpose overlap gather: res[n][co][oy][ox] = sum D / 6 -------
__global__ __launch_bounds__(256) void csa_gather(
    const float* __restrict__ D, float* __restrict__ res) {
  int id = blockIdx.x * 256 + threadIdx.x;
  if (id >= NB * BAND * HO * HO) return;
  int ox = id % HO;
  int t = id / HO;
  int oy = t % HO;
  t = t / HO;
  int co = t % BAND;
  int n = t / BAND;
  const float* Dn = D + (size_t)n * MV * PS;
  float s = 0.f;
  int kh0 = oy & 3;
  int kw0 = ox & 3;
  for (int kh = kh0; kh < 5; kh += 4) {
    int y = (oy - kh) >> 2;
    if (y < 0 || y >= 96) continue;
    for (int kw = kw0; kw < 5; kw += 4) {
      int x = (ox - kw) >> 2;
      if (x < 0 || x >= 96) continue;
      s += Dn[(size_t)(co * 25 + kh * 5 + kw) * PS + y * 96 + x];
    }
  }
  res[id] = s * (1.f / 6.f);
}

// ---------------------------------------------------------------------------
extern "C" void kernel_launch(void* const* d_in, const int* in_sizes, int n_in,
                              void* d_out, int out_size, void* d_ws,
                              size_t ws_size, hipStream_t stream) {
  const float* ms   = (const float*)d_in[0];
  const float* pan  = (const float*)d_in[1];
  const float* pan2 = (const float*)d_in[2];
  const float* wq = (const float*)d_in[3];
  const float* bq = (const float*)d_in[4];
  const float* wk = (const float*)d_in[5];
  const float* bk = (const float*)d_in[6];
  const float* wv = (const float*)d_in[7];
  const float* bv = (const float*)d_in[8];
  const float* wr = (const float*)d_in[9];
  const float* br = (const float*)d_in[10];
  float* out = (float*)d_out;

  char* ws = (char*)d_ws;
  float* k_fea = (float*)(ws + OFF_KFEA);
  float* v_fea = (float*)(ws + OFF_VFEA);
  float* n2    = (float*)(ws + OFF_N2);
  float* scale = (float*)(ws + OFF_SC);
  f16*   Kmat  = (f16*)(ws + OFF_KM);
  f16*   Vt    = (f16*)(ws + OFF_VT);
  f16*   Qt    = (f16*)(ws + OFF_QT);
  float* scoT  = (float*)(ws + OFF_ST);
  f16*   attnT = (f16*)(ws + OFF_AT);
  float* Dm    = (float*)(ws + OFF_D);
  float* res   = (float*)(ws + OFF_RES);

  dim3 b256(256);
  csa_conv3_1x64<<<dim3((NB * HK * HK + 255) / 256), b256, 0, stream>>>(
      pan2, wk, bk, k_fea, HK, HK);
  csa_conv3_8x8<<<dim3((NB * HK * HK + 255) / 256), b256, 0, stream>>>(
      ms, wv, bv, v_fea, HK, HK);
  csa_qmat<<<dim3((int)(((size_t)NB * PS * KDIM) / 256)), b256, 0, stream>>>(
      pan, wq, bq, Qt);
  csa_build_patches<<<dim3(NB * LP), b256, 0, stream>>>(k_fea, v_fea, Kmat, Vt,
                                                        n2);
  csa_max_scale<<<dim3(NB), b256, 0, stream>>>(n2, scale);

  // GEMM1: scoresT[PS][LP] = Qt[PS][KDIM] x Kmat[LP][KDIM]^T
  csa_gemm_f16<<<dim3(LP / 128, PS / 128, NB), b256, 0, stream>>>(
      Qt, Kmat, scoT, PS, LP, KDIM,
      (size_t)PS * KDIM, (size_t)LP * KDIM, (size_t)PS * LP);

  csa_softmax<<<dim3(PS / 4, NB), b256, 0, stream>>>(scoT, scale, attnT);

  // GEMM2: D[MV][PS] = Vt[MV][L] x attnT[PS][L]^T
  csa_gemm_f16<<<dim3(PS / 128, MV / 128, NB), b256, 0, stream>>>(
      Vt, attnT, Dm, MV, PS, L,
      (size_t)MV * L, (size_t)PS * L, (size_t)MV * PS);

  csa_gather<<<dim3((NB * BAND * HO * HO + 255) / 256), b256, 0, stream>>>(
      Dm, res);
  csa_conv3_8x8<<<dim3((NB * HO * HO + 255) / 256), b256, 0, stream>>>(
      res, wr, br, out, HO, HO);
}

// Round 3
// 302.563 us; speedup vs baseline: 2.9932x; 1.8284x over previous
//
#include <hip/hip_runtime.h>
#include <math.h>

// ---------------------------------------------------------------------------
// cross_scale_attention v3: implicit-A MFMA GEMM1 (no Qmat materialization)
//   qcl[n][385][385][64] f16 <- conv3(pan, wq, bq), channels-last, SAME-pad
//   kcl[n][96][96][64]   f16 <- conv3(pan2, wk, bk), channels-last
//   v_fea fp32           <- conv3(ms, wv, bv)
//   Kmat[n][l][(kh,kw,c)] f16 (640 rows, pad 0) + norms  <- kcl gather
//   Vt[n][m][l] f16 (256x576)                            <- v_fea gather
//   scoresT[n][p][l640] = implicit-Q x Kmat^T   (MFMA GEMM1, A from qcl)
//   attnT[n][p][l] f16  = softmax * 10/maxnorm
//   D[n][m][p] = Vt x attnT^T                   (MFMA GEMM2)
//   res gather (/6), final conv3 8x8 -> out fp32
// ---------------------------------------------------------------------------

typedef _Float16 f16;
typedef _Float16 f16x8 __attribute__((ext_vector_type(8)));
typedef float f32x4 __attribute__((ext_vector_type(4)));

namespace csa {
constexpr int NB   = 2;
constexpr int MID  = 64;
constexpr int BAND = 8;
constexpr int HK   = 96;
constexpr int HQ   = 384;
constexpr int HQP  = 385;           // padded q spatial
constexpr int LN   = 24;
constexpr int L    = 576;
constexpr int LP   = 640;
constexpr int PS   = 96 * 96;       // 9216
constexpr int KDIM = MID * 25;      // 1600
constexpr int VDIM = BAND * 25;     // 200
constexpr int MV   = 256;
constexpr int HO   = 385;
constexpr size_t QCLN = (size_t)HQP * HQP * MID;  // per-batch qcl elems

constexpr size_t align256(size_t x) { return (x + 255) & ~(size_t)255; }
constexpr size_t OFF_QCL  = 0;                                            // f16 NB*385*385*64
constexpr size_t OFF_KCL  = align256(OFF_QCL + (size_t)NB*QCLN*2);        // f16 NB*96*96*64
constexpr size_t OFF_VFEA = align256(OFF_KCL + (size_t)NB*HK*HK*MID*2);   // f32 NB*8*96*96
constexpr size_t OFF_N2   = align256(OFF_VFEA + (size_t)NB*BAND*HK*HK*4); // f32 NB*576
constexpr size_t OFF_SC   = align256(OFF_N2   + (size_t)NB*L*4);
constexpr size_t OFF_KM   = align256(OFF_SC   + 256);                     // f16 NB*640*1600
constexpr size_t OFF_VT   = align256(OFF_KM   + (size_t)NB*LP*KDIM*2);    // f16 NB*256*576
constexpr size_t OFF_ST   = align256(OFF_VT   + (size_t)NB*MV*L*2);       // f32 NB*9216*640
constexpr size_t OFF_AT   = align256(OFF_ST   + (size_t)NB*PS*LP*4);      // f16 NB*9216*576
constexpr size_t OFF_D    = align256(OFF_AT   + (size_t)NB*PS*L*2);       // f32 NB*256*9216
constexpr size_t OFF_RES  = align256(OFF_D    + (size_t)NB*MV*PS*4);      // f32 NB*8*385*385
}  // namespace csa
using namespace csa;

// ---------- conv3 1->64, channels-last f16 out, optional +1 zero pad --------
// out[n][y][x][c], y,x in [0,Hout); pixels with y>=H or x>=H are zero.
__global__ __launch_bounds__(256) void csa_conv_cl(
    const float* __restrict__ in, const float* __restrict__ w,
    const float* __restrict__ b, f16* __restrict__ out, int H, int Hout) {
  int id = blockIdx.x * 256 + threadIdx.x;
  int total = NB * Hout * Hout;
  if (id >= total) return;
  int x = id % Hout;
  int t = id / Hout;
  int y = t % Hout;
  int n = t / Hout;
  f16* op = out + (size_t)id * MID;
  if (y >= H || x >= H) {
    f16x8 z = {0, 0, 0, 0, 0, 0, 0, 0};
#pragma unroll
    for (int c8 = 0; c8 < 8; ++c8) *(f16x8*)(op + c8 * 8) = z;
    return;
  }
  const float* ip = in + (size_t)n * H * H;
  float p[9];
#pragma unroll
  for (int dy = 0; dy < 3; ++dy)
#pragma unroll
    for (int dx = 0; dx < 3; ++dx) {
      int yy = y + dy - 1, xx = x + dx - 1;
      p[dy * 3 + dx] = (yy >= 0 && yy < H && xx >= 0 && xx < H)
                           ? ip[(size_t)yy * H + xx] : 0.f;
    }
#pragma unroll
  for (int c8 = 0; c8 < 8; ++c8) {
    f16x8 o;
#pragma unroll
    for (int e = 0; e < 8; ++e) {
      int co = c8 * 8 + e;
      float acc = b[co];
#pragma unroll
      for (int k = 0; k < 9; ++k) acc = fmaf(p[k], w[co * 9 + k], acc);
      o[e] = (f16)(acc > 0.f ? acc : 0.01f * acc);
    }
    *(f16x8*)(op + c8 * 8) = o;
  }
}

// ------------------------- conv3: 8 in-ch -> 8 out-ch -----------------------
__global__ __launch_bounds__(256) void csa_conv3_8x8(
    const float* __restrict__ in, const float* __restrict__ w,
    const float* __restrict__ b, float* __restrict__ out, int H, int W) {
  int id = blockIdx.x * 256 + threadIdx.x;
  int total = NB * H * W;
  if (id >= total) return;
  int x = id % W;
  int t = id / W;
  int y = t % H;
  int n = t / H;
  const float* ip = in + (size_t)n * BAND * H * W;
  float p[BAND][9];
#pragma unroll
  for (int ci = 0; ci < BAND; ++ci)
#pragma unroll
    for (int dy = 0; dy < 3; ++dy)
#pragma unroll
      for (int dx = 0; dx < 3; ++dx) {
        int yy = y + dy - 1, xx = x + dx - 1;
        p[ci][dy * 3 + dx] = (yy >= 0 && yy < H && xx >= 0 && xx < W)
                                 ? ip[((size_t)ci * H + yy) * W + xx] : 0.f;
      }
  float* op = out + ((size_t)n * BAND * H + y) * W + x;
  for (int co = 0; co < BAND; ++co) {
    float acc = b[co];
#pragma unroll
    for (int ci = 0; ci < BAND; ++ci)
#pragma unroll
      for (int k = 0; k < 9; ++k)
        acc = fmaf(p[ci][k], w[(co * BAND + ci) * 9 + k], acc);
    acc = acc > 0.f ? acc : 0.01f * acc;
    op[(size_t)co * H * W] = acc;
  }
}

// ---- patches: Kmat[l][(kh,kw,c)] f16 (rows>=576 zero), Vt[m][l], norms² ----
__global__ __launch_bounds__(256) void csa_build_patches(
    const f16* __restrict__ kcl, const float* __restrict__ v_fea,
    f16* __restrict__ Kmat, f16* __restrict__ Vt, float* __restrict__ n2) {
  int blk = blockIdx.x;  // NB*LP blocks
  int n = blk / LP;
  int l = blk % LP;
  int tid = threadIdx.x;
  f16* krow = Kmat + ((size_t)n * LP + l) * KDIM;
  if (l >= L) {
    f16x8 z = {0, 0, 0, 0, 0, 0, 0, 0};
    for (int ch = tid; ch < 200; ch += 256) *(f16x8*)(krow + ch * 8) = z;
    return;
  }
  int i = l / LN, j = l % LN;
  const f16* kn = kcl + (size_t)n * HK * HK * MID;
  float ss = 0.f;
  // 1600 = 25 (kh,kw) x 64 c  ->  200 chunks of 8 f16
  for (int ch = tid; ch < 200; ch += 256) {
    int khkw = ch >> 3;
    int c0 = (ch & 7) * 8;
    int kh = khkw / 5, kw = khkw % 5;
    int r = (4 * i + kh + 95) % 97;
    int cc = (4 * j + kw + 95) % 97;
    f16x8 v = {0, 0, 0, 0, 0, 0, 0, 0};
    if (r < HK && cc < HK)
      v = *(const f16x8*)(kn + ((size_t)r * HK + cc) * MID + c0);
#pragma unroll
    for (int e = 0; e < 8; ++e) {
      float f = (float)v[e];
      ss += f * f;
    }
    *(f16x8*)(krow + ch * 8) = v;
  }
  for (int m = tid; m < MV; m += 256) {
    float v = 0.f;
    if (m < VDIM) {
      int kw = m % 5;
      int t = m / 5;
      int kh = t % 5;
      int c = t / 5;
      int r = (4 * i + kh + 95) % 97;
      int cc = (4 * j + kw + 95) % 97;
      v = (r < HK && cc < HK)
              ? v_fea[(((size_t)n * BAND + c) * HK + r) * HK + cc] : 0.f;
    }
    Vt[((size_t)n * MV + m) * L + l] = (f16)v;
  }
  __shared__ float red[256];
  red[tid] = ss;
  __syncthreads();
  for (int s = 128; s > 0; s >>= 1) {
    if (tid < s) red[tid] += red[tid + s];
    __syncthreads();
  }
  if (tid == 0) n2[n * L + l] = red[0];
}

// ---------------- scale[n] = 10 / sqrt(max_l norms2[n][l]) ------------------
__global__ __launch_bounds__(256) void csa_max_scale(
    const float* __restrict__ n2, float* __restrict__ scale) {
  int n = blockIdx.x;
  int tid = threadIdx.x;
  float m = 0.f;
  for (int l = tid; l < L; l += 256) m = fmaxf(m, n2[n * L + l]);
  __shared__ float red[256];
  red[tid] = m;
  __syncthreads();
  for (int s = 128; s > 0; s >>= 1) {
    if (tid < s) red[tid] = fmaxf(red[tid], red[tid + s]);
    __syncthreads();
  }
  if (tid == 0) scale[n] = 10.f / sqrtf(red[0]);
}

// --------------------------- MFMA GEMM helpers ------------------------------
__device__ __forceinline__ void gl_lds16(const f16* g, f16* s) {
  __builtin_amdgcn_global_load_lds(
      (const __attribute__((address_space(1))) void*)g,
      (__attribute__((address_space(3))) void*)s, 16, 0, 0);
}

// ------------- GEMM1: scoresT[p][l] = implicit-Q  x  Kmat^T -----------------
// A[p][k] = qcl[(4y+kh)*385 + 4x+kw][c], k = (kh*5+kw)*64 + c; p = y*96+x.
// BM=BN=128, BK=32, 4 waves, 16x16x32 f16 MFMA, fp32 out [PS][LP].
__global__ __launch_bounds__(256) void csa_gemm1(
    const f16* __restrict__ qcl, const f16* __restrict__ Km,
    float* __restrict__ C) {
  __shared__ __attribute__((aligned(16))) f16 As[4096];
  __shared__ __attribute__((aligned(16))) f16 Bs[4096];
  const int tid = threadIdx.x;
  const int w = tid >> 6;
  const int l = tid & 63;
  const int q = l >> 4;
  const int r = l & 15;
  const int nb = blockIdx.z;
  qcl += (size_t)nb * QCLN;
  Km += (size_t)nb * LP * KDIM;
  C += (size_t)nb * (size_t)PS * LP;
  const int bm = blockIdx.y * 128;
  const int bn = blockIdx.x * 128;
  const int wm = (w >> 1) * 64;
  const int wn = (w & 1) * 64;

  f32x4 acc[4][4];
#pragma unroll
  for (int i = 0; i < 4; ++i)
#pragma unroll
    for (int j = 0; j < 4; ++j) {
      f32x4 z = {0.f, 0.f, 0.f, 0.f};
      acc[i][j] = z;
    }

  const int p0 = bm + w * 16 + r;
  const int y0 = p0 / 96, x0 = p0 % 96;
  const int p1 = p0 + 64;
  const int y1 = p1 / 96, x1 = p1 % 96;
  const f16* a0 = qcl + ((size_t)(4 * y0) * HQP + 4 * x0) * MID + q * 8;
  const f16* a1 = qcl + ((size_t)(4 * y1) * HQP + 4 * x1) * MID + q * 8;
  const f16* gb0 = Km + (size_t)(bn + w * 16 + r) * KDIM + q * 8;
  const f16* gb1 = gb0 + (size_t)64 * KDIM;
  f16* lA0 = As + w * 512;
  f16* lA1 = As + 2048 + w * 512;
  f16* lB0 = Bs + w * 512;
  f16* lB1 = Bs + 2048 + w * 512;
  const int am = (w >> 1) * 4;
  const int bnn = (w & 1) * 4;

  int t = 0;
  for (int kh = 0; kh < 5; ++kh) {
    for (int kw = 0; kw < 5; ++kw) {
      const size_t offA = ((size_t)kh * HQP + kw) * MID;
#pragma unroll
      for (int half = 0; half < 2; ++half, ++t) {
        const size_t oA = offA + half * 32;
        const size_t oB = (size_t)t * 32;
        gl_lds16(a0 + oA, lA0);
        gl_lds16(a1 + oA, lA1);
        gl_lds16(gb0 + oB, lB0);
        gl_lds16(gb1 + oB, lB1);
        __syncthreads();
        f16x8 af[4], bf[4];
#pragma unroll
        for (int u = 0; u < 4; ++u) {
          af[u] = *(const f16x8*)&As[(am + u) * 512 + q * 128 + r * 8];
          bf[u] = *(const f16x8*)&Bs[(bnn + u) * 512 + q * 128 + r * 8];
        }
#pragma unroll
        for (int i = 0; i < 4; ++i)
#pragma unroll
          for (int j = 0; j < 4; ++j)
            acc[i][j] = __builtin_amdgcn_mfma_f32_16x16x32_f16(af[i], bf[j],
                                                               acc[i][j], 0, 0, 0);
        __syncthreads();
      }
    }
  }
  const int cn = bn + wn + r;
#pragma unroll
  for (int i = 0; i < 4; ++i) {
    int rm = bm + wm + i * 16 + q * 4;
#pragma unroll
    for (int j = 0; j < 4; ++j)
#pragma unroll
      for (int rr = 0; rr < 4; ++rr)
        C[(size_t)(rm + rr) * LP + cn + j * 16] = acc[i][j][rr];
  }
}

// --------------------- generic f16 MFMA GEMM (GEMM2) ------------------------
__global__ __launch_bounds__(256) void csa_gemm_f16(
    const f16* __restrict__ A, const f16* __restrict__ Bt,
    float* __restrict__ C, int M, int N, int K,
    size_t strideA, size_t strideB, size_t strideC) {
  __shared__ __attribute__((aligned(16))) f16 As[4096];
  __shared__ __attribute__((aligned(16))) f16 Bs[4096];
  const int tid = threadIdx.x;
  const int w = tid >> 6;
  const int l = tid & 63;
  const int q = l >> 4;
  const int r = l & 15;
  const int nb = blockIdx.z;
  A += (size_t)nb * strideA;
  Bt += (size_t)nb * strideB;
  C += (size_t)nb * strideC;
  const int bm = blockIdx.y * 128;
  const int bn = blockIdx.x * 128;
  const int wm = (w >> 1) * 64;
  const int wn = (w & 1) * 64;

  f32x4 acc[4][4];
#pragma unroll
  for (int i = 0; i < 4; ++i)
#pragma unroll
    for (int j = 0; j < 4; ++j) {
      f32x4 z = {0.f, 0.f, 0.f, 0.f};
      acc[i][j] = z;
    }

  const f16* ga0 = A + (size_t)(bm + w * 16 + r) * K + q * 8;
  const f16* ga1 = ga0 + (size_t)64 * K;
  const f16* gb0 = Bt + (size_t)(bn + w * 16 + r) * K + q * 8;
  const f16* gb1 = gb0 + (size_t)64 * K;
  f16* lA0 = As + w * 512;
  f16* lA1 = As + 2048 + w * 512;
  f16* lB0 = Bs + w * 512;
  f16* lB1 = Bs + 2048 + w * 512;
  const int am = (w >> 1) * 4;
  const int bnn = (w & 1) * 4;

  for (int k0 = 0; k0 < K; k0 += 32) {
    gl_lds16(ga0 + k0, lA0);
    gl_lds16(ga1 + k0, lA1);
    gl_lds16(gb0 + k0, lB0);
    gl_lds16(gb1 + k0, lB1);
    __syncthreads();
    f16x8 af[4], bf[4];
#pragma unroll
    for (int u = 0; u < 4; ++u) {
      af[u] = *(const f16x8*)&As[(am + u) * 512 + q * 128 + r * 8];
      bf[u] = *(const f16x8*)&Bs[(bnn + u) * 512 + q * 128 + r * 8];
    }
#pragma unroll
    for (int i = 0; i < 4; ++i)
#pragma unroll
      for (int j = 0; j < 4; ++j)
        acc[i][j] =
            __builtin_amdgcn_mfma_f32_16x16x32_f16(af[i], bf[j], acc[i][j], 0, 0, 0);
    __syncthreads();
  }

  const int cn = bn + wn + r;
#pragma unroll
  for (int i = 0; i < 4; ++i) {
    int rm = bm + wm + i * 16 + q * 4;
#pragma unroll
    for (int j = 0; j < 4; ++j)
#pragma unroll
      for (int rr = 0; rr < 4; ++rr)
        C[(size_t)(rm + rr) * N + cn + j * 16] = acc[i][j][rr];
  }
}

// ------- row softmax: attnT[p][l] f16 = softmax_l(scoresT[p][l]*scale) ------
__global__ __launch_bounds__(256) void csa_softmax(
    const float* __restrict__ scoresT, const float* __restrict__ scale,
    f16* __restrict__ attnT) {
  const int wv = threadIdx.x >> 6;
  const int lane = threadIdx.x & 63;
  const int p = blockIdx.x * 4 + wv;
  const int n = blockIdx.y;
  const float sc = scale[n];
  const float* row = scoresT + ((size_t)n * PS + p) * LP;
  float v[9];
  float m = -1e30f;
#pragma unroll
  for (int j = 0; j < 9; ++j) {
    v[j] = row[lane + j * 64] * sc;
    m = fmaxf(m, v[j]);
  }
#pragma unroll
  for (int off = 32; off > 0; off >>= 1) m = fmaxf(m, __shfl_xor(m, off));
  float e[9], s = 0.f;
#pragma unroll
  for (int j = 0; j < 9; ++j) {
    e[j] = __expf(v[j] - m);
    s += e[j];
  }
#pragma unroll
  for (int off = 32; off > 0; off >>= 1) s += __shfl_xor(s, off);
  const float inv = 1.f / s;
  f16* orow = attnT + ((size_t)n * PS + p) * L;
#pragma unroll
  for (int j = 0; j < 9; ++j) orow[lane + j * 64] = (f16)(e[j] * inv);
}

// ------ conv_transpose overlap gather: res[n][co][oy][ox] = sum D / 6 -------
__global__ __launch_bounds__(256) void csa_gather(
    const float* __restrict__ D, float* __restrict__ res) {
  int id = blockIdx.x * 256 + threadIdx.x;
  if (id >= NB * BAND * HO * HO) return;
  int ox = id % HO;
  int t = id / HO;
  int oy = t % HO;
  t = t / HO;
  int co = t % BAND;
  int n = t / BAND;
  const float* Dn = D + (size_t)n * MV * PS;
  float s = 0.f;
  int kh0 = oy & 3;
  int kw0 = ox & 3;
  for (int kh = kh0; kh < 5; kh += 4) {
    int y = (oy - kh) >> 2;
    if (y < 0 || y >= 96) continue;
    for (int kw = kw0; kw < 5; kw += 4) {
      int x = (ox - kw) >> 2;
      if (x < 0 || x >= 96) continue;
      s += Dn[(size_t)(co * 25 + kh * 5 + kw) * PS + y * 96 + x];
    }
  }
  res[id] = s * (1.f / 6.f);
}

// ---------------------------------------------------------------------------
extern "C" void kernel_launch(void* const* d_in, const int* in_sizes, int n_in,
                              void* d_out, int out_size, void* d_ws,
                              size_t ws_size, hipStream_t stream) {
  const float* ms   = (const float*)d_in[0];
  const float* pan  = (const float*)d_in[1];
  const float* pan2 = (const float*)d_in[2];
  const float* wq = (const float*)d_in[3];
  const float* bq = (const float*)d_in[4];
  const float* wk = (const float*)d_in[5];
  const float* bk = (const float*)d_in[6];
  const float* wv = (const float*)d_in[7];
  const float* bv = (const float*)d_in[8];
  const float* wr = (const float*)d_in[9];
  const float* br = (const float*)d_in[10];
  float* out = (float*)d_out;

  char* ws = (char*)d_ws;
  f16*   qcl   = (f16*)(ws + OFF_QCL);
  f16*   kcl   = (f16*)(ws + OFF_KCL);
  float* v_fea = (float*)(ws + OFF_VFEA);
  float* n2    = (float*)(ws + OFF_N2);
  float* scale = (float*)(ws + OFF_SC);
  f16*   Kmat  = (f16*)(ws + OFF_KM);
  f16*   Vt    = (f16*)(ws + OFF_VT);
  float* scoT  = (float*)(ws + OFF_ST);
  f16*   attnT = (f16*)(ws + OFF_AT);
  float* Dm    = (float*)(ws + OFF_D);
  float* res   = (float*)(ws + OFF_RES);

  dim3 b256(256);
  csa_conv_cl<<<dim3((NB * HQP * HQP + 255) / 256), b256, 0, stream>>>(
      pan, wq, bq, qcl, HQ, HQP);
  csa_conv_cl<<<dim3((NB * HK * HK + 255) / 256), b256, 0, stream>>>(
      pan2, wk, bk, kcl, HK, HK);
  csa_conv3_8x8<<<dim3((NB * HK * HK + 255) / 256), b256, 0, stream>>>(
      ms, wv, bv, v_fea, HK, HK);
  csa_build_patches<<<dim3(NB * LP), b256, 0, stream>>>(kcl, v_fea, Kmat, Vt,
                                                        n2);
  csa_max_scale<<<dim3(NB), b256, 0, stream>>>(n2, scale);

  // GEMM1: scoresT[PS][LP] = implicit-Q x Kmat^T
  csa_gemm1<<<dim3(LP / 128, PS / 128, NB), b256, 0, stream>>>(qcl, Kmat,
                                                               scoT);

  csa_softmax<<<dim3(PS / 4, NB), b256, 0, stream>>>(scoT, scale, attnT);

  // GEMM2: D[MV][PS] = Vt[MV][L] x attnT[PS][L]^T
  csa_gemm_f16<<<dim3(PS / 128, MV / 128, NB), b256, 0, stream>>>(
      Vt, attnT, Dm, MV, PS, L,
      (size_t)MV * L, (size_t)PS * L, (size_t)MV * PS);

  csa_gather<<<dim3((NB * BAND * HO * HO + 255) / 256), b256, 0, stream>>>(
      Dm, res);
  csa_conv3_8x8<<<dim3((NB * HO * HO + 255) / 256), b256, 0, stream>>>(
      res, wr, br, out, HO, HO);
}

// Round 4
// 279.360 us; speedup vs baseline: 3.2418x; 1.0831x over previous
//
#include <hip/hip_runtime.h>
#include <math.h>

// ---------------------------------------------------------------------------
// cross_scale_attention v4: phase-split q layout -> coalesced implicit-A GEMM1
//   qps[n][f][385][97][64] f16 <- conv3(pan, wq, bq); entry (f,y',xi) = pixel
//        (y', 4*xi+f), zero if y'>=384 or 4*xi+f>=384  (SAME-pad)
//   kcl[n][96][96][64]   f16 <- conv3(pan2, wk, bk), channels-last
//   v_fea fp32           <- conv3(ms, wv, bv)
//   Kmat[n][l][(kh,kw,c)] f16 (640 rows, pad 0) + norms  <- kcl gather
//   Vt[n][m][l] f16 (256x576)
//   scoresT[n][p][l640] = implicit-Q x Kmat^T   (MFMA GEMM1, A from qps)
//   attnT[n][p][l] f16  = softmax * 10/maxnorm
//   D[n][m][p] = Vt x attnT^T                   (MFMA GEMM2)
//   res gather (/6), final conv3 8x8 -> out fp32
// ---------------------------------------------------------------------------

typedef _Float16 f16;
typedef _Float16 f16x8 __attribute__((ext_vector_type(8)));
typedef float f32x4 __attribute__((ext_vector_type(4)));

namespace csa {
constexpr int NB   = 2;
constexpr int MID  = 64;
constexpr int BAND = 8;
constexpr int HK   = 96;
constexpr int HQ   = 384;
constexpr int HQP  = 385;
constexpr int XI   = 97;            // xi range per phase
constexpr int LN   = 24;
constexpr int L    = 576;
constexpr int LP   = 640;
constexpr int PS   = 96 * 96;       // 9216
constexpr int KDIM = MID * 25;      // 1600
constexpr int VDIM = BAND * 25;     // 200
constexpr int MV   = 256;
constexpr int HO   = 385;
constexpr size_t QPSN = (size_t)4 * HQP * XI * MID;  // per-batch qps elems

constexpr size_t align256(size_t x) { return (x + 255) & ~(size_t)255; }
constexpr size_t OFF_QPS  = 0;                                            // f16 NB*QPSN
constexpr size_t OFF_KCL  = align256(OFF_QPS + (size_t)NB*QPSN*2);        // f16 NB*96*96*64
constexpr size_t OFF_VFEA = align256(OFF_KCL + (size_t)NB*HK*HK*MID*2);   // f32 NB*8*96*96
constexpr size_t OFF_N2   = align256(OFF_VFEA + (size_t)NB*BAND*HK*HK*4);
constexpr size_t OFF_SC   = align256(OFF_N2   + (size_t)NB*L*4);
constexpr size_t OFF_KM   = align256(OFF_SC   + 256);                     // f16 NB*640*1600
constexpr size_t OFF_VT   = align256(OFF_KM   + (size_t)NB*LP*KDIM*2);    // f16 NB*256*576
constexpr size_t OFF_ST   = align256(OFF_VT   + (size_t)NB*MV*L*2);       // f32 NB*9216*640
constexpr size_t OFF_AT   = align256(OFF_ST   + (size_t)NB*PS*LP*4);      // f16 NB*9216*576
constexpr size_t OFF_D    = align256(OFF_AT   + (size_t)NB*PS*L*2);       // f32 NB*256*9216
constexpr size_t OFF_RES  = align256(OFF_D    + (size_t)NB*MV*PS*4);      // f32 NB*8*385*385
}  // namespace csa
using namespace csa;

// -------- conv3 1->64 channels-last f16, phase-split output for q -----------
// out[((n*4+f)*385+y')*97+xi][c]; value = conv(y', 4*xi+f) or 0 if padded.
__global__ __launch_bounds__(256) void csa_convq_ps(
    const float* __restrict__ in, const float* __restrict__ w,
    const float* __restrict__ b, f16* __restrict__ out) {
  int id = blockIdx.x * 256 + threadIdx.x;
  int total = NB * 4 * HQP * XI;
  if (id >= total) return;
  int xi = id % XI;
  int t = id / XI;
  int yp = t % HQP;
  t /= HQP;
  int f = t % 4;
  int n = t / 4;
  int xp = 4 * xi + f;
  f16* op = out + (size_t)id * MID;
  if (yp >= HQ || xp >= HQ) {
    f16x8 z = {0, 0, 0, 0, 0, 0, 0, 0};
#pragma unroll
    for (int c8 = 0; c8 < 8; ++c8) *(f16x8*)(op + c8 * 8) = z;
    return;
  }
  const float* ip = in + (size_t)n * HQ * HQ;
  float p[9];
#pragma unroll
  for (int dy = 0; dy < 3; ++dy)
#pragma unroll
    for (int dx = 0; dx < 3; ++dx) {
      int yy = yp + dy - 1, xx = xp + dx - 1;
      p[dy * 3 + dx] = (yy >= 0 && yy < HQ && xx >= 0 && xx < HQ)
                           ? ip[(size_t)yy * HQ + xx] : 0.f;
    }
#pragma unroll
  for (int c8 = 0; c8 < 8; ++c8) {
    f16x8 o;
#pragma unroll
    for (int e = 0; e < 8; ++e) {
      int co = c8 * 8 + e;
      float acc = b[co];
#pragma unroll
      for (int k = 0; k < 9; ++k) acc = fmaf(p[k], w[co * 9 + k], acc);
      o[e] = (f16)(acc > 0.f ? acc : 0.01f * acc);
    }
    *(f16x8*)(op + c8 * 8) = o;
  }
}

// ---------- conv3 1->64, channels-last f16 out (for k features) -------------
__global__ __launch_bounds__(256) void csa_conv_cl(
    const float* __restrict__ in, const float* __restrict__ w,
    const float* __restrict__ b, f16* __restrict__ out, int H) {
  int id = blockIdx.x * 256 + threadIdx.x;
  int total = NB * H * H;
  if (id >= total) return;
  int x = id % H;
  int t = id / H;
  int y = t % H;
  int n = t / H;
  f16* op = out + (size_t)id * MID;
  const float* ip = in + (size_t)n * H * H;
  float p[9];
#pragma unroll
  for (int dy = 0; dy < 3; ++dy)
#pragma unroll
    for (int dx = 0; dx < 3; ++dx) {
      int yy = y + dy - 1, xx = x + dx - 1;
      p[dy * 3 + dx] = (yy >= 0 && yy < H && xx >= 0 && xx < H)
                           ? ip[(size_t)yy * H + xx] : 0.f;
    }
#pragma unroll
  for (int c8 = 0; c8 < 8; ++c8) {
    f16x8 o;
#pragma unroll
    for (int e = 0; e < 8; ++e) {
      int co = c8 * 8 + e;
      float acc = b[co];
#pragma unroll
      for (int k = 0; k < 9; ++k) acc = fmaf(p[k], w[co * 9 + k], acc);
      o[e] = (f16)(acc > 0.f ? acc : 0.01f * acc);
    }
    *(f16x8*)(op + c8 * 8) = o;
  }
}

// ------------------------- conv3: 8 in-ch -> 8 out-ch -----------------------
__global__ __launch_bounds__(256) void csa_conv3_8x8(
    const float* __restrict__ in, const float* __restrict__ w,
    const float* __restrict__ b, float* __restrict__ out, int H, int W) {
  int id = blockIdx.x * 256 + threadIdx.x;
  int total = NB * H * W;
  if (id >= total) return;
  int x = id % W;
  int t = id / W;
  int y = t % H;
  int n = t / H;
  const float* ip = in + (size_t)n * BAND * H * W;
  float p[BAND][9];
#pragma unroll
  for (int ci = 0; ci < BAND; ++ci)
#pragma unroll
    for (int dy = 0; dy < 3; ++dy)
#pragma unroll
      for (int dx = 0; dx < 3; ++dx) {
        int yy = y + dy - 1, xx = x + dx - 1;
        p[ci][dy * 3 + dx] = (yy >= 0 && yy < H && xx >= 0 && xx < W)
                                 ? ip[((size_t)ci * H + yy) * W + xx] : 0.f;
      }
  float* op = out + ((size_t)n * BAND * H + y) * W + x;
  for (int co = 0; co < BAND; ++co) {
    float acc = b[co];
#pragma unroll
    for (int ci = 0; ci < BAND; ++ci)
#pragma unroll
      for (int k = 0; k < 9; ++k)
        acc = fmaf(p[ci][k], w[(co * BAND + ci) * 9 + k], acc);
    acc = acc > 0.f ? acc : 0.01f * acc;
    op[(size_t)co * H * W] = acc;
  }
}

// ---- patches: Kmat[l][(kh,kw,c)] f16 (rows>=576 zero), Vt[m][l], norms² ----
__global__ __launch_bounds__(256) void csa_build_patches(
    const f16* __restrict__ kcl, const float* __restrict__ v_fea,
    f16* __restrict__ Kmat, f16* __restrict__ Vt, float* __restrict__ n2) {
  int blk = blockIdx.x;  // NB*LP blocks
  int n = blk / LP;
  int l = blk % LP;
  int tid = threadIdx.x;
  f16* krow = Kmat + ((size_t)n * LP + l) * KDIM;
  if (l >= L) {
    f16x8 z = {0, 0, 0, 0, 0, 0, 0, 0};
    for (int ch = tid; ch < 200; ch += 256) *(f16x8*)(krow + ch * 8) = z;
    return;
  }
  int i = l / LN, j = l % LN;
  const f16* kn = kcl + (size_t)n * HK * HK * MID;
  float ss = 0.f;
  for (int ch = tid; ch < 200; ch += 256) {
    int khkw = ch >> 3;
    int c0 = (ch & 7) * 8;
    int kh = khkw / 5, kw = khkw % 5;
    int r = (4 * i + kh + 95) % 97;
    int cc = (4 * j + kw + 95) % 97;
    f16x8 v = {0, 0, 0, 0, 0, 0, 0, 0};
    if (r < HK && cc < HK)
      v = *(const f16x8*)(kn + ((size_t)r * HK + cc) * MID + c0);
#pragma unroll
    for (int e = 0; e < 8; ++e) {
      float fv = (float)v[e];
      ss += fv * fv;
    }
    *(f16x8*)(krow + ch * 8) = v;
  }
  for (int m = tid; m < MV; m += 256) {
    float v = 0.f;
    if (m < VDIM) {
      int kw = m % 5;
      int t = m / 5;
      int kh = t % 5;
      int c = t / 5;
      int r = (4 * i + kh + 95) % 97;
      int cc = (4 * j + kw + 95) % 97;
      v = (r < HK && cc < HK)
              ? v_fea[(((size_t)n * BAND + c) * HK + r) * HK + cc] : 0.f;
    }
    Vt[((size_t)n * MV + m) * L + l] = (f16)v;
  }
  __shared__ float red[256];
  red[tid] = ss;
  __syncthreads();
  for (int s = 128; s > 0; s >>= 1) {
    if (tid < s) red[tid] += red[tid + s];
    __syncthreads();
  }
  if (tid == 0) n2[n * L + l] = red[0];
}

// ---------------- scale[n] = 10 / sqrt(max_l norms2[n][l]) ------------------
__global__ __launch_bounds__(256) void csa_max_scale(
    const float* __restrict__ n2, float* __restrict__ scale) {
  int n = blockIdx.x;
  int tid = threadIdx.x;
  float m = 0.f;
  for (int l = tid; l < L; l += 256) m = fmaxf(m, n2[n * L + l]);
  __shared__ float red[256];
  red[tid] = m;
  __syncthreads();
  for (int s = 128; s > 0; s >>= 1) {
    if (tid < s) red[tid] = fmaxf(red[tid], red[tid + s]);
    __syncthreads();
  }
  if (tid == 0) scale[n] = 10.f / sqrtf(red[0]);
}

// --------------------------- MFMA GEMM helpers ------------------------------
__device__ __forceinline__ void gl_lds16(const f16* g, f16* s) {
  __builtin_amdgcn_global_load_lds(
      (const __attribute__((address_space(1))) void*)g,
      (__attribute__((address_space(3))) void*)s, 16, 0, 0);
}

// ------------- GEMM1: scoresT[p][l] = implicit-Q  x  Kmat^T -----------------
// A[p][k], k=(kh*5+kw)*64+c. A row p -> (y=p/96, x=p%96); element =
// qps[f=kw&3][4y+kh][x + (kw>>2)][c]. 16-lane groups have fixed y (96%16==0),
// so lane addr = uniform + r*128B + q*16B -> fully coalesced staging.
__global__ __launch_bounds__(256) void csa_gemm1(
    const f16* __restrict__ qps, const f16* __restrict__ Km,
    float* __restrict__ C) {
  __shared__ __attribute__((aligned(16))) f16 As[4096];
  __shared__ __attribute__((aligned(16))) f16 Bs[4096];
  const int tid = threadIdx.x;
  const int w = tid >> 6;
  const int l = tid & 63;
  const int q = l >> 4;
  const int r = l & 15;
  const int nb = blockIdx.z;
  qps += (size_t)nb * QPSN;
  Km += (size_t)nb * LP * KDIM;
  C += (size_t)nb * (size_t)PS * LP;
  const int bm = blockIdx.y * 128;
  const int bn = blockIdx.x * 128;
  const int wm = (w >> 1) * 64;
  const int wn = (w & 1) * 64;

  f32x4 acc[4][4];
#pragma unroll
  for (int i = 0; i < 4; ++i)
#pragma unroll
    for (int j = 0; j < 4; ++j) {
      f32x4 z = {0.f, 0.f, 0.f, 0.f};
      acc[i][j] = z;
    }

  const int pg0 = bm + w * 16;            // wave-uniform, multiple of 16
  const int y0 = pg0 / 96, x0 = pg0 % 96;
  const int pg1 = pg0 + 64;
  const int y1 = pg1 / 96, x1 = pg1 % 96;
  const int la = r * MID + q * 8;         // lane offset in f16

  const f16* gb0 = Km + (size_t)(bn + w * 16 + r) * KDIM + q * 8;
  const f16* gb1 = gb0 + (size_t)64 * KDIM;
  f16* lA0 = As + w * 512;
  f16* lA1 = As + 2048 + w * 512;
  f16* lB0 = Bs + w * 512;
  f16* lB1 = Bs + 2048 + w * 512;
  const int am = (w >> 1) * 4;
  const int bnn = (w & 1) * 4;

  int t = 0;
  for (int kh = 0; kh < 5; ++kh) {
    for (int kw = 0; kw < 5; ++kw) {
      const size_t u0 =
          (((size_t)(kw & 3) * HQP + (4 * y0 + kh)) * XI + x0 + (kw >> 2)) * MID;
      const size_t u1 =
          (((size_t)(kw & 3) * HQP + (4 * y1 + kh)) * XI + x1 + (kw >> 2)) * MID;
#pragma unroll
      for (int half = 0; half < 2; ++half, ++t) {
        const size_t oA = (size_t)half * 32 + la;
        const size_t oB = (size_t)t * 32;
        gl_lds16(qps + u0 + oA, lA0);
        gl_lds16(qps + u1 + oA, lA1);
        gl_lds16(gb0 + oB, lB0);
        gl_lds16(gb1 + oB, lB1);
        __syncthreads();
        f16x8 af[4], bf[4];
#pragma unroll
        for (int u = 0; u < 4; ++u) {
          af[u] = *(const f16x8*)&As[(am + u) * 512 + q * 128 + r * 8];
          bf[u] = *(const f16x8*)&Bs[(bnn + u) * 512 + q * 128 + r * 8];
        }
#pragma unroll
        for (int i = 0; i < 4; ++i)
#pragma unroll
          for (int j = 0; j < 4; ++j)
            acc[i][j] = __builtin_amdgcn_mfma_f32_16x16x32_f16(af[i], bf[j],
                                                               acc[i][j], 0, 0, 0);
        __syncthreads();
      }
    }
  }
  const int cn = bn + wn + r;
#pragma unroll
  for (int i = 0; i < 4; ++i) {
    int rm = bm + wm + i * 16 + q * 4;
#pragma unroll
    for (int j = 0; j < 4; ++j)
#pragma unroll
      for (int rr = 0; rr < 4; ++rr)
        C[(size_t)(rm + rr) * LP + cn + j * 16] = acc[i][j][rr];
  }
}

// --------------------- generic f16 MFMA GEMM (GEMM2) ------------------------
__global__ __launch_bounds__(256) void csa_gemm_f16(
    const f16* __restrict__ A, const f16* __restrict__ Bt,
    float* __restrict__ C, int M, int N, int K,
    size_t strideA, size_t strideB, size_t strideC) {
  __shared__ __attribute__((aligned(16))) f16 As[4096];
  __shared__ __attribute__((aligned(16))) f16 Bs[4096];
  const int tid = threadIdx.x;
  const int w = tid >> 6;
  const int l = tid & 63;
  const int q = l >> 4;
  const int r = l & 15;
  const int nb = blockIdx.z;
  A += (size_t)nb * strideA;
  Bt += (size_t)nb * strideB;
  C += (size_t)nb * strideC;
  const int bm = blockIdx.y * 128;
  const int bn = blockIdx.x * 128;
  const int wm = (w >> 1) * 64;
  const int wn = (w & 1) * 64;

  f32x4 acc[4][4];
#pragma unroll
  for (int i = 0; i < 4; ++i)
#pragma unroll
    for (int j = 0; j < 4; ++j) {
      f32x4 z = {0.f, 0.f, 0.f, 0.f};
      acc[i][j] = z;
    }

  const f16* ga0 = A + (size_t)(bm + w * 16 + r) * K + q * 8;
  const f16* ga1 = ga0 + (size_t)64 * K;
  const f16* gb0 = Bt + (size_t)(bn + w * 16 + r) * K + q * 8;
  const f16* gb1 = gb0 + (size_t)64 * K;
  f16* lA0 = As + w * 512;
  f16* lA1 = As + 2048 + w * 512;
  f16* lB0 = Bs + w * 512;
  f16* lB1 = Bs + 2048 + w * 512;
  const int am = (w >> 1) * 4;
  const int bnn = (w & 1) * 4;

  for (int k0 = 0; k0 < K; k0 += 32) {
    gl_lds16(ga0 + k0, lA0);
    gl_lds16(ga1 + k0, lA1);
    gl_lds16(gb0 + k0, lB0);
    gl_lds16(gb1 + k0, lB1);
    __syncthreads();
    f16x8 af[4], bf[4];
#pragma unroll
    for (int u = 0; u < 4; ++u) {
      af[u] = *(const f16x8*)&As[(am + u) * 512 + q * 128 + r * 8];
      bf[u] = *(const f16x8*)&Bs[(bnn + u) * 512 + q * 128 + r * 8];
    }
#pragma unroll
    for (int i = 0; i < 4; ++i)
#pragma unroll
      for (int j = 0; j < 4; ++j)
        acc[i][j] =
            __builtin_amdgcn_mfma_f32_16x16x32_f16(af[i], bf[j], acc[i][j], 0, 0, 0);
    __syncthreads();
  }

  const int cn = bn + wn + r;
#pragma unroll
  for (int i = 0; i < 4; ++i) {
    int rm = bm + wm + i * 16 + q * 4;
#pragma unroll
    for (int j = 0; j < 4; ++j)
#pragma unroll
      for (int rr = 0; rr < 4; ++rr)
        C[(size_t)(rm + rr) * N + cn + j * 16] = acc[i][j][rr];
  }
}

// ------- row softmax: attnT[p][l] f16 = softmax_l(scoresT[p][l]*scale) ------
__global__ __launch_bounds__(256) void csa_softmax(
    const float* __restrict__ scoresT, const float* __restrict__ scale,
    f16* __restrict__ attnT) {
  const int wv = threadIdx.x >> 6;
  const int lane = threadIdx.x & 63;
  const int p = blockIdx.x * 4 + wv;
  const int n = blockIdx.y;
  const float sc = scale[n];
  const float* row = scoresT + ((size_t)n * PS + p) * LP;
  float v[9];
  float m = -1e30f;
#pragma unroll
  for (int j = 0; j < 9; ++j) {
    v[j] = row[lane + j * 64] * sc;
    m = fmaxf(m, v[j]);
  }
#pragma unroll
  for (int off = 32; off > 0; off >>= 1) m = fmaxf(m, __shfl_xor(m, off));
  float e[9], s = 0.f;
#pragma unroll
  for (int j = 0; j < 9; ++j) {
    e[j] = __expf(v[j] - m);
    s += e[j];
  }
#pragma unroll
  for (int off = 32; off > 0; off >>= 1) s += __shfl_xor(s, off);
  const float inv = 1.f / s;
  f16* orow = attnT + ((size_t)n * PS + p) * L;
#pragma unroll
  for (int j = 0; j < 9; ++j) orow[lane + j * 64] = (f16)(e[j] * inv);
}

// ------ conv_transpose overlap gather: res[n][co][oy][ox] = sum D / 6 -------
__global__ __launch_bounds__(256) void csa_gather(
    const float* __restrict__ D, float* __restrict__ res) {
  int id = blockIdx.x * 256 + threadIdx.x;
  if (id >= NB * BAND * HO * HO) return;
  int ox = id % HO;
  int t = id / HO;
  int oy = t % HO;
  t = t / HO;
  int co = t % BAND;
  int n = t / BAND;
  const float* Dn = D + (size_t)n * MV * PS;
  float s = 0.f;
  int kh0 = oy & 3;
  int kw0 = ox & 3;
  for (int kh = kh0; kh < 5; kh += 4) {
    int y = (oy - kh) >> 2;
    if (y < 0 || y >= 96) continue;
    for (int kw = kw0; kw < 5; kw += 4) {
      int x = (ox - kw) >> 2;
      if (x < 0 || x >= 96) continue;
      s += Dn[(size_t)(co * 25 + kh * 5 + kw) * PS + y * 96 + x];
    }
  }
  res[id] = s * (1.f / 6.f);
}

// ---------------------------------------------------------------------------
extern "C" void kernel_launch(void* const* d_in, const int* in_sizes, int n_in,
                              void* d_out, int out_size, void* d_ws,
                              size_t ws_size, hipStream_t stream) {
  const float* ms   = (const float*)d_in[0];
  const float* pan  = (const float*)d_in[1];
  const float* pan2 = (const float*)d_in[2];
  const float* wq = (const float*)d_in[3];
  const float* bq = (const float*)d_in[4];
  const float* wk = (const float*)d_in[5];
  const float* bk = (const float*)d_in[6];
  const float* wv = (const float*)d_in[7];
  const float* bv = (const float*)d_in[8];
  const float* wr = (const float*)d_in[9];
  const float* br = (const float*)d_in[10];
  float* out = (float*)d_out;

  char* ws = (char*)d_ws;
  f16*   qps   = (f16*)(ws + OFF_QPS);
  f16*   kcl   = (f16*)(ws + OFF_KCL);
  float* v_fea = (float*)(ws + OFF_VFEA);
  float* n2    = (float*)(ws + OFF_N2);
  float* scale = (float*)(ws + OFF_SC);
  f16*   Kmat  = (f16*)(ws + OFF_KM);
  f16*   Vt    = (f16*)(ws + OFF_VT);
  float* scoT  = (float*)(ws + OFF_ST);
  f16*   attnT = (f16*)(ws + OFF_AT);
  float* Dm    = (float*)(ws + OFF_D);
  float* res   = (float*)(ws + OFF_RES);

  dim3 b256(256);
  csa_convq_ps<<<dim3((NB * 4 * HQP * XI + 255) / 256), b256, 0, stream>>>(
      pan, wq, bq, qps);
  csa_conv_cl<<<dim3((NB * HK * HK + 255) / 256), b256, 0, stream>>>(
      pan2, wk, bk, kcl, HK);
  csa_conv3_8x8<<<dim3((NB * HK * HK + 255) / 256), b256, 0, stream>>>(
      ms, wv, bv, v_fea, HK, HK);
  csa_build_patches<<<dim3(NB * LP), b256, 0, stream>>>(kcl, v_fea, Kmat, Vt,
                                                        n2);
  csa_max_scale<<<dim3(NB), b256, 0, stream>>>(n2, scale);

  // GEMM1: scoresT[PS][LP] = implicit-Q x Kmat^T
  csa_gemm1<<<dim3(LP / 128, PS / 128, NB), b256, 0, stream>>>(qps, Kmat,
                                                               scoT);

  csa_softmax<<<dim3(PS / 4, NB), b256, 0, stream>>>(scoT, scale, attnT);

  // GEMM2: D[MV][PS] = Vt[MV][L] x attnT[PS][L]^T
  csa_gemm_f16<<<dim3(PS / 128, MV / 128, NB), b256, 0, stream>>>(
      Vt, attnT, Dm, MV, PS, L,
      (size_t)MV * L, (size_t)PS * L, (size_t)MV * PS);

  csa_gather<<<dim3((NB * BAND * HO * HO + 255) / 256), b256, 0, stream>>>(
      Dm, res);
  csa_conv3_8x8<<<dim3((NB * HO * HO + 255) / 256), b256, 0, stream>>>(
      res, wr, br, out, HO, HO);
}